// Round 12
// baseline (205.234 us; speedup 1.0000x reference)
//
#include <hip/hip_runtime.h>
#include <hip/hip_bf16.h>

#define N_NODES 100000
#define N_EDGES 3200000
#define N_QUADS (N_EDGES / 4)

#define NTH 1024
#define PACK_BLOCKS 512

// ---- hist kernels: P=5, PART=20224 (80.9 KB LDS, 2 blocks/CU = 161.8 KB) ----
#define P_PARTS 5
#define PART    20224                    // 5*20224 = 101120 >= N
#define SLICES  100
#define SLICE_E (N_EDGES / SLICES)       // 32000 (%4 == 0)
#define BLOCKS_H (P_PARTS * SLICES)      // 500

// ---------------- workspace layout (bytes) ----------------
#define OFF_BPART 0         // double[512*5] per-block stats partials (all written)
#define OFF_CONST 20480     // float[136]: A32,B32,C32,U32,GB,SCC
#define OFF_DEG   21056     // float[101120] (zeroed by pack) -> ends 425536
#define OFF_ACC   425536    // float[101120] -> ends 830016
#define OFF_DINV  830016    // float[N]
#define OFF_GS    1230016   // float[N]
#define OFF_SRC32 1630016   // int[N_EDGES] (12.8 MB)
#define OFF_DST32 14430016  // int[N_EDGES] (12.8 MB) -> ends ~27.2 MB

// per-wave int64-vs-int32 detection: high words of first 64 int64 slots
__device__ __forceinline__ bool detect_is64(const void* ei) {
    const int* p = (const int*)ei;
    int lane = threadIdx.x & 63;
    int hi = p[2 * lane + 1];
    unsigned long long m = __ballot(hi != 0);
    return m == 0ull;  // wave-uniform
}

// ---- K1: zero degf + pack edges to int32 + per-block BN stats partials ----
__global__ __launch_bounds__(NTH) void pack_kernel(
        const float* __restrict__ x, const void* __restrict__ ei,
        double* __restrict__ bpart, float* __restrict__ degf,
        int* __restrict__ src32, int* __restrict__ dst32) {
    __shared__ double sh[5][16];
    bool is64 = detect_is64(ei);
    int nthr = PACK_BLOCKS * NTH;
    int tid = blockIdx.x * NTH + threadIdx.x;

    for (int i = tid; i < P_PARTS * PART; i += nthr) degf[i] = 0.f;

    if (is64) {
        const long long* srcp = (const long long*)ei;
        const long long* dstp = srcp + N_EDGES;
        for (int q = tid; q < N_QUADS; q += nthr) {
            longlong2 s01 = ((const longlong2*)srcp)[2 * q];
            longlong2 s23 = ((const longlong2*)srcp)[2 * q + 1];
            longlong2 d01 = ((const longlong2*)dstp)[2 * q];
            longlong2 d23 = ((const longlong2*)dstp)[2 * q + 1];
            ((int4*)src32)[q] = make_int4((int)s01.x, (int)s01.y, (int)s23.x, (int)s23.y);
            ((int4*)dst32)[q] = make_int4((int)d01.x, (int)d01.y, (int)d23.x, (int)d23.y);
        }
    } else {
        const int* srcp = (const int*)ei;
        const int* dstp = srcp + N_EDGES;
        for (int q = tid; q < N_QUADS; q += nthr) {
            ((int4*)src32)[q] = ((const int4*)srcp)[q];
            ((int4*)dst32)[q] = ((const int4*)dstp)[q];
        }
    }

    // BN stats partial (non-atomic; every block writes its slot)
    double a0 = 0, a1 = 0, a2 = 0, a3 = 0, a4 = 0;
    if (tid < N_NODES) {
        float2 v = ((const float2*)x)[tid];
        double x0 = v.x, x1 = v.y;
        a0 = x0; a1 = x1; a2 = x0 * x0; a3 = x1 * x1; a4 = x0 * x1;
    }
    for (int off = 32; off; off >>= 1) {
        a0 += __shfl_down(a0, off);
        a1 += __shfl_down(a1, off);
        a2 += __shfl_down(a2, off);
        a3 += __shfl_down(a3, off);
        a4 += __shfl_down(a4, off);
    }
    int w = threadIdx.x >> 6;
    if ((threadIdx.x & 63) == 0) {
        sh[0][w] = a0; sh[1][w] = a1; sh[2][w] = a2; sh[3][w] = a3; sh[4][w] = a4;
    }
    __syncthreads();
    if (threadIdx.x == 0) {
        double t0 = 0, t1 = 0, t2 = 0, t3 = 0, t4 = 0;
        for (int i = 0; i < 16; i++) {
            t0 += sh[0][i]; t1 += sh[1][i]; t2 += sh[2][i]; t3 += sh[3][i]; t4 += sh[4][i];
        }
        double* bp = bpart + blockIdx.x * 5;
        bp[0] = t0; bp[1] = t1; bp[2] = t2; bp[3] = t3; bp[4] = t4;
    }
}

// ---- K2: degree histogram (P=5) + consts computed by block 0 (parallel reduce) ----
__global__ __launch_bounds__(NTH, 8) void deg_kernel(
        const int* __restrict__ dst32, float* __restrict__ degf,
        const double* __restrict__ bpart,
        const float* __restrict__ w1, const float* __restrict__ b1,
        const float* __restrict__ gamma, const float* __restrict__ beta,
        const float* __restrict__ w2, const float* __restrict__ b2,
        const float* __restrict__ gcn_w, const float* __restrict__ wb,
        const float* __restrict__ gcn_b, const float* __restrict__ bb,
        float* __restrict__ consts) {
    __shared__ float hist[PART];
    __shared__ float sV[32];
    __shared__ double red[8][5];
    int p = blockIdx.x % P_PARTS;
    int slice = blockIdx.x / P_PARTS;
    int base = p * PART;

    for (int i = threadIdx.x; i < PART; i += NTH) hist[i] = 0.f;
    __syncthreads();

    int e0 = slice * SLICE_E, e1 = e0 + SLICE_E;
    for (int e = e0 + threadIdx.x * 4; e < e1; e += NTH * 4) {
        int4 d4 = *(const int4*)(dst32 + e);
        unsigned l0 = (unsigned)(d4.x - base);
        unsigned l1 = (unsigned)(d4.y - base);
        unsigned l2 = (unsigned)(d4.z - base);
        unsigned l3 = (unsigned)(d4.w - base);
        if (l0 < PART) atomicAdd(&hist[l0], 1.0f);
        if (l1 < PART) atomicAdd(&hist[l1], 1.0f);
        if (l2 < PART) atomicAdd(&hist[l2], 1.0f);
        if (l3 < PART) atomicAdd(&hist[l3], 1.0f);
    }
    __syncthreads();
    for (int i = threadIdx.x; i < PART; i += NTH) {
        float v = hist[i];
        if (v != 0.f) unsafeAtomicAdd(&degf[base + i], v);
    }

    // ---- block 0: reduce bpart -> encoder/head constants ----
    if (blockIdx.x == 0) {
        int t = threadIdx.x;
        // parallel reduce: threads 0..511, each loads its block's 5 partials
        double r0 = 0, r1 = 0, r2 = 0, r3 = 0, r4 = 0;
        if (t < PACK_BLOCKS) {
            const double* bp = bpart + t * 5;
            r0 = bp[0]; r1 = bp[1]; r2 = bp[2]; r3 = bp[3]; r4 = bp[4];
        }
        for (int off = 32; off; off >>= 1) {
            r0 += __shfl_down(r0, off);
            r1 += __shfl_down(r1, off);
            r2 += __shfl_down(r2, off);
            r3 += __shfl_down(r3, off);
            r4 += __shfl_down(r4, off);
        }
        int w = t >> 6;
        if ((t & 63) == 0 && w < 8) {
            red[w][0] = r0; red[w][1] = r1; red[w][2] = r2; red[w][3] = r3; red[w][4] = r4;
        }
        __syncthreads();
        if (t < 32) {
            int c = t;
            double s0 = 0, s1 = 0, s2 = 0, s3 = 0, s4 = 0;
            for (int i = 0; i < 8; i++) {
                s0 += red[i][0]; s1 += red[i][1]; s2 += red[i][2];
                s3 += red[i][3]; s4 += red[i][4];
            }
            double invN = 1.0 / (double)N_NODES;
            double m0 = s0 * invN, m1 = s1 * invN;
            double e00 = s2 * invN, e11 = s3 * invN, e01 = s4 * invN;
            double a = w1[2 * c], b = w1[2 * c + 1], tt = b1[c];
            double meanH = a * m0 + b * m1 + tt;
            double eh2 = a * a * e00 + b * b * e11 + 2.0 * a * b * e01 +
                         2.0 * tt * (a * m0 + b * m1) + tt * tt;
            double var = eh2 - meanH * meanH;
            double inv = 1.0 / sqrt(var + 1e-5);
            float sc = (float)((double)gamma[c] * inv);
            float shift = beta[c] - (float)meanH * sc;
            consts[c]      = (float)a * sc;
            consts[32 + c] = (float)b * sc;
            consts[64 + c] = (float)tt * sc + shift;
            float vc = 0.f;
            for (int j = 0; j < 32; j++) vc += wb[j] * gcn_w[j * 32 + c];
            sV[c] = vc;
        }
        __syncthreads();
        if (t < 32) {
            float u = 0.f;
            for (int c = 0; c < 32; c++) u += sV[c] * w2[c * 32 + t];
            consts[96 + t] = u;
            float gb = b2[t] * sV[t];
            for (int off = 16; off; off >>= 1) gb += __shfl_down(gb, off, 32);
            float pv = wb[t] * gcn_b[t];
            for (int off = 16; off; off >>= 1) pv += __shfl_down(pv, off, 32);
            if (t == 0) {
                consts[128] = gb;            // GB = b2 . v
                consts[129] = pv + bb[0];    // SCC
            }
        }
    }
}

// ---- K3: encoder (scalar): gs[n] = dinv * (GB + sum_c PReLU(Ax0+Bx1+C) U[c]) ----
__global__ __launch_bounds__(NTH) void encoder_kernel(
        const float* __restrict__ x, const float* __restrict__ consts,
        const float* __restrict__ prelu_a, const float* __restrict__ degf,
        float* __restrict__ dinv, float* __restrict__ gs, float* __restrict__ acc) {
    __shared__ float sA[32], sB[32], sC[32], sU[32];
    __shared__ float sGB;
    if (threadIdx.x < 32) {
        sA[threadIdx.x] = consts[threadIdx.x];
        sB[threadIdx.x] = consts[32 + threadIdx.x];
        sC[threadIdx.x] = consts[64 + threadIdx.x];
        sU[threadIdx.x] = consts[96 + threadIdx.x];
    }
    if (threadIdx.x == 0) sGB = consts[128];
    __syncthreads();
    float alpha = prelu_a[0];
    int n = blockIdx.x * NTH + threadIdx.x;
    if (n < N_NODES) {
        float2 xv = ((const float2*)x)[n];
        float g = sGB;
#pragma unroll
        for (int c = 0; c < 32; c++) {
            float hb = sA[c] * xv.x + sB[c] * xv.y + sC[c];
            float pc = hb >= 0.f ? hb : alpha * hb;
            g += pc * sU[c];
        }
        float di = rsqrtf(degf[n] + 1.0f);
        float gg = di * g;
        dinv[n] = di;
        gs[n] = gg;
        acc[n] = gg;  // self-loop term; finalize multiplies by dinv
    }
}

// ---- K4: scatter hist acc[dst] += gs[src] (P=5, 4-edge unroll) ----
__global__ __launch_bounds__(NTH, 8) void scatter_kernel(
        const int* __restrict__ src32, const int* __restrict__ dst32,
        const float* __restrict__ gs, float* __restrict__ acc) {
    __shared__ float hist[PART];
    int p = blockIdx.x % P_PARTS;
    int slice = blockIdx.x / P_PARTS;
    int base = p * PART;

    for (int i = threadIdx.x; i < PART; i += NTH) hist[i] = 0.f;
    __syncthreads();

    int e0 = slice * SLICE_E, e1 = e0 + SLICE_E;
    for (int e = e0 + threadIdx.x * 4; e < e1; e += NTH * 4) {
        int4 d4 = *(const int4*)(dst32 + e);
        int4 s4 = *(const int4*)(src32 + e);
        unsigned l0 = (unsigned)(d4.x - base);
        unsigned l1 = (unsigned)(d4.y - base);
        unsigned l2 = (unsigned)(d4.z - base);
        unsigned l3 = (unsigned)(d4.w - base);
        if (l0 < PART) atomicAdd(&hist[l0], gs[s4.x]);
        if (l1 < PART) atomicAdd(&hist[l1], gs[s4.y]);
        if (l2 < PART) atomicAdd(&hist[l2], gs[s4.z]);
        if (l3 < PART) atomicAdd(&hist[l3], gs[s4.w]);
    }
    __syncthreads();
    for (int i = threadIdx.x; i < PART; i += NTH) {
        float v = hist[i];
        if (v != 0.f) unsafeAtomicAdd(&acc[base + i], v);
    }
}

// ---- K5: finalize: out = dinv*acc + SCC ----
__global__ void finalize_kernel(const float* __restrict__ dinv, const float* __restrict__ acc,
                                const float* __restrict__ consts, float* __restrict__ out) {
    float scc = consts[129];
    int n = blockIdx.x * blockDim.x + threadIdx.x;
    if (n < N_NODES) out[n] = dinv[n] * acc[n] + scc;
}

extern "C" void kernel_launch(void* const* d_in, const int* in_sizes, int n_in,
                              void* d_out, int out_size, void* d_ws, size_t ws_size,
                              hipStream_t stream) {
    const float* x       = (const float*)d_in[0];
    const void*  ei      = d_in[1];
    const float* w1      = (const float*)d_in[2];
    const float* b1      = (const float*)d_in[3];
    const float* bn_g    = (const float*)d_in[4];
    const float* bn_b    = (const float*)d_in[5];
    const float* prelu_a = (const float*)d_in[6];
    const float* w2      = (const float*)d_in[7];
    const float* b2      = (const float*)d_in[8];
    const float* gcn_w   = (const float*)d_in[9];
    const float* gcn_b   = (const float*)d_in[10];
    const float* wb      = (const float*)d_in[11];
    const float* bb      = (const float*)d_in[12];
    float* out = (float*)d_out;

    char* base = (char*)d_ws;
    double* bpart  = (double*)(base + OFF_BPART);
    float*  consts = (float*)(base + OFF_CONST);
    float*  degf   = (float*)(base + OFF_DEG);
    float*  acc    = (float*)(base + OFF_ACC);
    float*  dinv   = (float*)(base + OFF_DINV);
    float*  gs     = (float*)(base + OFF_GS);
    int*    src32  = (int*)(base + OFF_SRC32);
    int*    dst32  = (int*)(base + OFF_DST32);

    pack_kernel<<<PACK_BLOCKS, NTH, 0, stream>>>(x, ei, bpart, degf, src32, dst32);
    deg_kernel<<<BLOCKS_H, NTH, 0, stream>>>(dst32, degf, bpart,
        w1, b1, bn_g, bn_b, w2, b2, gcn_w, wb, gcn_b, bb, consts);
    encoder_kernel<<<(N_NODES + NTH - 1) / NTH, NTH, 0, stream>>>(
        x, consts, prelu_a, degf, dinv, gs, acc);
    scatter_kernel<<<BLOCKS_H, NTH, 0, stream>>>(src32, dst32, gs, acc);
    finalize_kernel<<<(N_NODES + 255) / 256, 256, 0, stream>>>(dinv, acc, consts, out);
}